// Round 13
// baseline (59.596 us; speedup 1.0000x reference)
//
#include <hip/hip_runtime.h>

#define HID 96
#define NHEADS 4
#define FEAT 124
#define EPS_LN 1e-5f
#define NROWS 4096          // B*N
#define NB 2048             // N per batch
#define NSPLIT 16

typedef __attribute__((ext_vector_type(8))) short bf16x8;
typedef __attribute__((ext_vector_type(4))) float f32x4;
typedef __attribute__((ext_vector_type(2))) unsigned int uint2v;
typedef __attribute__((ext_vector_type(4))) unsigned int uint4v;

__device__ __forceinline__ unsigned short f2bf(float x) {
    unsigned int u = __float_as_uint(x);
    unsigned int r = (u + 0x7FFFu + ((u >> 16) & 1u)) >> 16;
    return (unsigned short)r;
}
__device__ __forceinline__ float bf2f(unsigned short h) {
    return __uint_as_float(((unsigned int)h) << 16);
}

// ============================================================ W fragment pack
__global__ __launch_bounds__(64) void wpack_kernel(
    const float* __restrict__ Wq, const float* __restrict__ Wk,
    const float* __restrict__ Wv, unsigned short* __restrict__ wf)
{
    int bid = blockIdx.x;
    int mat = bid / 18, kc = (bid / 6) % 3, jt = bid % 6;
    int lane = threadIdx.x;
    const float* W = (mat == 0) ? Wq : (mat == 1) ? Wk : Wv;
    int j = jt * 16 + (lane & 15);
    int t0 = kc * 32 + (lane >> 4) * 8;
    bf16x8 hi, lo;
    #pragma unroll
    for (int e = 0; e < 8; ++e) {
        float v = W[(t0 + e) * HID + j];
        unsigned short h = f2bf(v);
        hi[e] = (short)h;
        lo[e] = (short)f2bf(v - bf2f(h));
    }
    *(bf16x8*)(wf + ((size_t)(bid * 2 + 0) * 64 + lane) * 8) = hi;
    *(bf16x8*)(wf + ((size_t)(bid * 2 + 1) * 64 + lane) * 8) = lo;
}

// ============================================================ QKV via MFMA
__global__ __launch_bounds__(64) void qkvfrag_kernel(
    const float* __restrict__ x, const float* __restrict__ pos_CA,
    const float* __restrict__ bq, const float* __restrict__ bk,
    const float* __restrict__ bv, const unsigned short* __restrict__ wf,
    unsigned short* __restrict__ khi,
    unsigned short* __restrict__ qhi, unsigned short* __restrict__ qlo,
    unsigned short* __restrict__ vfr)
{
    int nt = blockIdx.x / 3, mat = blockIdx.x % 3;
    int lane = threadIdx.x;
    int row0 = nt * 16;
    int b = row0 >> 11;
    int ntb = nt & 127;                 // per-batch 16-row tile
    int T = ntb >> 1;                   // per-batch 32-row tile
    __shared__ float xs[16][97];
    for (int i = lane; i < 16 * HID; i += 64)
        xs[i / HID][i % HID] = x[(size_t)row0 * HID + i];
    __syncthreads();

    int n = lane & 15, g = lane >> 4;
    bf16x8 xh[3], xl[3];
    #pragma unroll
    for (int kc = 0; kc < 3; ++kc)
        #pragma unroll
        for (int e = 0; e < 8; ++e) {
            float v = xs[n][kc * 32 + g * 8 + e];
            unsigned short h = f2bf(v);
            xh[kc][e] = (short)h;
            xl[kc][e] = (short)f2bf(v - bf2f(h));
        }

    const float* bias = (mat == 0) ? bq : (mat == 1) ? bk : bv;

    #pragma unroll
    for (int jt = 0; jt < 6; ++jt) {
        f32x4 acc;
        #pragma unroll
        for (int r = 0; r < 4; ++r) acc[r] = bias[jt * 16 + 4 * g + r];
        #pragma unroll
        for (int kc = 0; kc < 3; ++kc) {
            const unsigned short* A = wf + (size_t)(((mat * 3 + kc) * 6 + jt) * 2) * 512;
            bf16x8 ah = *(const bf16x8*)(A + lane * 8);
            bf16x8 al = *(const bf16x8*)(A + 512 + lane * 8);
            acc = __builtin_amdgcn_mfma_f32_16x16x32_bf16(ah, xh[kc], acc, 0, 0, 0);
            acc = __builtin_amdgcn_mfma_f32_16x16x32_bf16(al, xh[kc], acc, 0, 0, 0);
            acc = __builtin_amdgcn_mfma_f32_16x16x32_bf16(ah, xl[kc], acc, 0, 0, 0);
        }
        if (mat < 2) {
            int jg0 = jt * 16 + 4 * g;
            int h = jg0 / 24;
            int d0 = jg0 - 24 * h;
            int bh = b * NHEADS + h;
            size_t base = ((size_t)(bh * 128 + ntb) * 64 + n + 16 * (d0 >> 3)) * 8 + (d0 & 7);
            unsigned short h0 = f2bf(acc[0]), h1 = f2bf(acc[1]);
            unsigned short h2 = f2bf(acc[2]), h3 = f2bf(acc[3]);
            uint2v hv = { (unsigned int)h0 | ((unsigned int)h1 << 16),
                          (unsigned int)h2 | ((unsigned int)h3 << 16) };
            if (mat == 0) {
                *(uint2v*)(qhi + base) = hv;
                unsigned short l0 = f2bf(acc[0] - bf2f(h0)), l1 = f2bf(acc[1] - bf2f(h1));
                unsigned short l2 = f2bf(acc[2] - bf2f(h2)), l3 = f2bf(acc[3] - bf2f(h3));
                uint2v lv = { (unsigned int)l0 | ((unsigned int)l1 << 16),
                              (unsigned int)l2 | ((unsigned int)l3 << 16) };
                *(uint2v*)(qlo + base) = lv;
            } else {
                *(uint2v*)(khi + base) = hv;
            }
        } else {
            int g2 = (ntb & 1) * 2 + (n >> 3);
            #pragma unroll
            for (int r = 0; r < 4; ++r) {
                int jg = jt * 16 + 4 * g + r;
                int h = jg / 24;
                int d = jg - 24 * h;
                int bh = b * NHEADS + h;
                size_t vidx = (((size_t)(bh * 64 + T) * 2 + (d >> 4)) * 64
                               + (d & 15) + 16 * g2) * 8 + (n & 7);
                vfr[vidx] = f2bf(acc[r]);
            }
        }
    }

    if (mat == 2) {
        {
            int h = g;
            int bh = b * NHEADS + h;
            size_t fi = ((size_t)(bh * 128 + ntb) * 64 + 48 + n) * 8;
            bf16x8 zz = {0, 0, 0, 0, 0, 0, 0, 0};
            *(bf16x8*)(khi + fi) = zz;
            *(bf16x8*)(qhi + fi) = zz;
            *(bf16x8*)(qlo + fi) = zz;
        }
        if (lane < 4) {
            int col = 14 + (lane & 1);
            int g2 = (ntb & 1) * 2 + (lane >> 1);
            bf16x8 zz = {0, 0, 0, 0, 0, 0, 0, 0};
            #pragma unroll
            for (int h = 0; h < NHEADS; ++h) {
                int bh = b * NHEADS + h;
                *(bf16x8*)(vfr + (((size_t)(bh * 64 + T) * 2 + 1) * 64 + col + 16 * g2) * 8) = zz;
            }
        }
        {
            int row = row0 + n;
            int h = g;
            int bh = b * NHEADS + h;
            int g2 = (ntb & 1) * 2 + (n >> 3);
            #pragma unroll
            for (int rem = 0; rem < 6; ++rem) {
                int c = rem % 3;
                bool ishi = rem < 3;
                float val = pos_CA[(size_t)row * 3 + c];
                unsigned short hv = f2bf(val);
                unsigned short sv = ishi ? hv : f2bf(val - bf2f(hv));
                int col = (ishi ? 8 : 11) + c;
                vfr[(((size_t)(bh * 64 + T) * 2 + 1) * 64 + col + 16 * g2) * 8 + (n & 7)] = sv;
            }
        }
    }
}

// ============================================================ MFMA flash attention
// 4 q-tiles/wave (r12 structure) with ORDERING FIX: pfrag accessed through a
// single element type (unsigned int) + compiler memory barriers at the two
// phase boundaries, so the PV-phase LDS reads can never be hoisted above the
// pack-phase LDS writes (r12's failure mode).
__global__ __launch_bounds__(256) void attn_mfma_kernel(
    const unsigned short* __restrict__ khi,
    const unsigned short* __restrict__ qhi, const unsigned short* __restrict__ qlo,
    const unsigned short* __restrict__ vfr,
    float* __restrict__ part)
{
    __shared__ unsigned int pfrag[4][4][2][64][4];     // [wave][qi][ktile][lane][dword] 32KB
    int wid = threadIdx.x >> 6;
    int lane = threadIdx.x & 63;
    int task = blockIdx.x * 4 + wid;
    int qtp = task & 31;
    int bh = (task >> 5) & 7;
    int ks = task >> 8;
    int qcol = lane & 15, g = lane >> 4;

    bf16x8 qh4[4], ql4[4];
    #pragma unroll
    for (int qi = 0; qi < 4; ++qi) {
        int qt = qtp * 4 + qi;
        qh4[qi] = *(const bf16x8*)(qhi + ((size_t)(bh * 128 + qt) * 64 + lane) * 8);
        ql4[qi] = *(const bf16x8*)(qlo + ((size_t)(bh * 128 + qt) * 64 + lane) * 8);
    }

    f32x4 z = {0.f, 0.f, 0.f, 0.f};
    f32x4 acc[4][2] = {{z, z}, {z, z}, {z, z}, {z, z}};
    float ll[4] = {0.f, 0.f, 0.f, 0.f};

    #pragma unroll
    for (int t8 = 0; t8 < 32 / NSPLIT; ++t8) {
        int kt0 = ks * (128 / NSPLIT) + t8 * 4;
        const unsigned short* kb = khi + ((size_t)(bh * 128 + kt0) * 64 + lane) * 8;
        bf16x8 kh[4];
        #pragma unroll
        for (int i = 0; i < 4; ++i)
            kh[i] = *(const bf16x8*)(kb + i * 512);

        // ---- QK + softmax + pack for all 4 q-tiles
        #pragma unroll
        for (int qi = 0; qi < 4; ++qi) {
            f32x4 s[4];
            #pragma unroll
            for (int i = 0; i < 4; ++i) {
                s[i] = __builtin_amdgcn_mfma_f32_16x16x32_bf16(kh[i], qh4[qi], z, 0, 0, 0);
                s[i] = __builtin_amdgcn_mfma_f32_16x16x32_bf16(kh[i], ql4[qi], s[i], 0, 0, 0);
            }
            float ts = 0.f;
            #pragma unroll
            for (int i = 0; i < 4; ++i)
                #pragma unroll
                for (int r = 0; r < 4; ++r) {
                    float pv = __expf(s[i][r]);
                    s[i][r] = pv;
                    ts += pv;
                }
            ts += __shfl_xor(ts, 16, 64);
            ts += __shfl_xor(ts, 32, 64);
            ll[qi] += ts;

            #pragma unroll
            for (int t = 0; t < 4; ++t) {
                int lp = qcol + 16 * (2 * (t & 1) + (g >> 1));
                unsigned int w0, w1;
                asm("v_cvt_pk_bf16_f32 %0, %1, %2" : "=v"(w0) : "v"(s[t][0]), "v"(s[t][1]));
                asm("v_cvt_pk_bf16_f32 %0, %1, %2" : "=v"(w1) : "v"(s[t][2]), "v"(s[t][3]));
                unsigned int* dst = &pfrag[wid][qi][t >> 1][lp][(g & 1) * 2];
                dst[0] = w0; dst[1] = w1;
            }
        }

        asm volatile("" ::: "memory");   // pack writes may not sink below PV reads

        // ---- load V
        int T0 = ks * (64 / NSPLIT) + t8 * 2;
        const unsigned short* vb = vfr + ((size_t)(bh * 64 + T0) * 2 * 64 + lane) * 8;
        bf16x8 v00 = *(const bf16x8*)(vb);
        bf16x8 v01 = *(const bf16x8*)(vb + 512);
        bf16x8 v10 = *(const bf16x8*)(vb + 1024);
        bf16x8 v11 = *(const bf16x8*)(vb + 1536);

        // ---- PV for all 4 q-tiles
        #pragma unroll
        for (int qi = 0; qi < 4; ++qi) {
            uint4v u0 = *(const uint4v*)&pfrag[wid][qi][0][lane][0];
            uint4v u1 = *(const uint4v*)&pfrag[wid][qi][1][lane][0];
            bf16x8 pf0 = __builtin_bit_cast(bf16x8, u0);
            bf16x8 pf1 = __builtin_bit_cast(bf16x8, u1);
            acc[qi][0] = __builtin_amdgcn_mfma_f32_16x16x32_bf16(v00, pf0, acc[qi][0], 0, 0, 0);
            acc[qi][0] = __builtin_amdgcn_mfma_f32_16x16x32_bf16(v10, pf1, acc[qi][0], 0, 0, 0);
            acc[qi][1] = __builtin_amdgcn_mfma_f32_16x16x32_bf16(v01, pf0, acc[qi][1], 0, 0, 0);
            acc[qi][1] = __builtin_amdgcn_mfma_f32_16x16x32_bf16(v11, pf1, acc[qi][1], 0, 0, 0);
        }

        asm volatile("" ::: "memory");   // next-iter pack writes may not rise above reads
    }

    // partial: [bh][qt][ks][qrow 16][32]: 0..29 acc(vd), 30 l
    #pragma unroll
    for (int qi = 0; qi < 4; ++qi) {
        int qt = qtp * 4 + qi;
        float* pp = part + ((size_t)((bh * 128 + qt) * NSPLIT + ks) * 16 + qcol) * 32;
        #pragma unroll
        for (int r = 0; r < 4; ++r) pp[g * 4 + r] = acc[qi][0][r];
        if (g < 3) {
            #pragma unroll
            for (int r = 0; r < 4; ++r) pp[16 + g * 4 + r] = acc[qi][1][r];
        } else {
            pp[28] = acc[qi][1][0];
            pp[29] = acc[qi][1][1];
            pp[30] = ll[qi];
        }
    }
}

// ============================================================ combine + finalize
__global__ __launch_bounds__(128) void finalize_kernel(
    const float* __restrict__ part,
    const float* __restrict__ pos_CA, const float* __restrict__ pos_CB,
    const float* __restrict__ x,
    const float* __restrict__ Wo, const float* __restrict__ bo,
    const float* __restrict__ g1, const float* __restrict__ b1,
    const float* __restrict__ g2, const float* __restrict__ b2,
    float* __restrict__ out)
{
    int row0 = blockIdx.x * 2;
    int tid = threadIdx.x;
    __shared__ float fsL[2][FEAT];
    __shared__ float cawS[2][NHEADS][3];
    __shared__ float st[2][2][2];

    #pragma unroll
    for (int it = 0; it < 2; ++it) {
        int T = tid + it * 128;
        if (T < 240) {
            int r = T / 120, u = T % 120;
            int h = u / 30, vd = u % 30;
            int row = row0 + r;
            int b = row >> 11, n = row & (NB - 1);
            int bh = b * NHEADS + h;
            const float* pb = part + ((size_t)((bh * 128 + (n >> 4)) * NSPLIT) * 16 + (n & 15)) * 32;
            float A = 0.f, L = 0.f, A2 = 0.f;
            #pragma unroll 4
            for (int ks = 0; ks < NSPLIT; ++ks) {
                const float* pk = pb + ks * (16 * 32);
                A += pk[vd];
                L += pk[30];
                if (vd >= 24 && vd < 27) A2 += pk[vd + 3];
            }
            if (vd < 24) fsL[r][h * 24 + vd] = A / L;
            else if (vd < 27) cawS[r][h][vd - 24] = (A + A2) / L;
        }
    }
    __syncthreads();

    if (tid >= 96 && tid < 104) {
        int i2 = tid - 96;
        int r = i2 >> 2, h = i2 & 3;
        int row = row0 + r;
        int n = row & (NB - 1);
        float cax = pos_CA[(size_t)row * 3 + 0];
        float cay = pos_CA[(size_t)row * 3 + 1];
        float caz = pos_CA[(size_t)row * 3 + 2];
        float cbx = pos_CB[(size_t)row * 3 + 0];
        float cby = pos_CB[(size_t)row * 3 + 1];
        float cbz = pos_CB[(size_t)row * 3 + 2];
        float e1x = cbx - cax, e1y = cby - cay, e1z = cbz - caz;
        float n1 = sqrtf(e1x * e1x + e1y * e1y + e1z * e1z);
        bool valid1 = n1 > 1e-6f;
        float inv1 = 1.f / fmaxf(n1, 1e-12f);
        float ax = e1x * inv1, ay = e1y * inv1, az = e1z * inv1;
        float e2x = ay, e2y = -ax, e2z = 0.f;
        float n2a = sqrtf(e2x * e2x + e2y * e2y);
        if (n2a < 1e-6f) { e2x = -az; e2y = 0.f; e2z = ax; }
        float n2 = sqrtf(e2x * e2x + e2y * e2y + e2z * e2z);
        bool valid2 = n2 > 1e-6f;
        float inv2 = 1.f / fmaxf(n2, 1e-12f);
        float bx = e2x * inv2, by = e2y * inv2, bz = e2z * inv2;
        float cx = ay * bz - az * by;
        float cy = az * bx - ax * bz;
        float cz = ax * by - ay * bx;
        bool valid = valid1 && valid2 && (n < NB - 1);
        float F00, F01, F02, F10, F11, F12, F20, F21, F22;
        if (valid) { F00 = ax; F10 = ay; F20 = az;
                     F01 = bx; F11 = by; F21 = bz;
                     F02 = cx; F12 = cy; F22 = cz; }
        else { F00 = 1.f; F01 = 0.f; F02 = 0.f;
               F10 = 0.f; F11 = 1.f; F12 = 0.f;
               F20 = 0.f; F21 = 0.f; F22 = 1.f; }
        float b0 = cbx - cawS[r][h][0];
        float b1v = cby - cawS[r][h][1];
        float b2v = cbz - cawS[r][h][2];
        float dist = sqrtf(b0 * b0 + b1v * b1v + b2v * b2v);
        float p0 = F00 * b0 + F01 * b1v + F02 * b2v;
        float p1 = F10 * b0 + F11 * b1v + F12 * b2v;
        float p2 = F20 * b0 + F21 * b1v + F22 * b2v;
        float pn = sqrtf(p0 * p0 + p1 * p1 + p2 * p2);
        float invp = 1.f / (pn + 1e-10f);
        fsL[r][HID + h * 3 + 0] = p0;
        fsL[r][HID + h * 3 + 1] = p1;
        fsL[r][HID + h * 3 + 2] = p2;
        fsL[r][HID + 12 + h] = dist;
        fsL[r][HID + 16 + h * 3 + 0] = p0 * invp;
        fsL[r][HID + 16 + h * 3 + 1] = p1 * invp;
        fsL[r][HID + 16 + h * 3 + 2] = p2 * invp;
    }
    __syncthreads();

    float y0 = 0.f, y1 = 0.f;
    if (tid < HID) {
        float bj = bo[tid];
        y0 = bj; y1 = bj;
        #pragma unroll 4
        for (int i = 0; i < FEAT; ++i) {
            float w = Wo[i * HID + tid];
            y0 = fmaf(fsL[0][i], w, y0);
            y1 = fmaf(fsL[1][i], w, y1);
        }
    }

    {
        float s0 = y0, q0 = y0 * y0, s1 = y1, q1 = y1 * y1;
        #pragma unroll
        for (int d = 1; d < 64; d <<= 1) {
            s0 += __shfl_xor(s0, d, 64); q0 += __shfl_xor(q0, d, 64);
            s1 += __shfl_xor(s1, d, 64); q1 += __shfl_xor(q1, d, 64);
        }
        if ((tid & 63) == 0) {
            int w = tid >> 6;
            st[0][w][0] = s0; st[0][w][1] = q0;
            st[1][w][0] = s1; st[1][w][1] = q1;
        }
    }
    __syncthreads();
    float mean0 = (st[0][0][0] + st[0][1][0]) * (1.0f / HID);
    float var0  = (st[0][0][1] + st[0][1][1]) * (1.0f / HID) - mean0 * mean0;
    float mean1 = (st[1][0][0] + st[1][1][0]) * (1.0f / HID);
    float var1  = (st[1][0][1] + st[1][1][1]) * (1.0f / HID) - mean1 * mean1;
    __syncthreads();

    float r0 = 0.f, r1 = 0.f;
    if (tid < HID) {
        float gg = g1[tid], bb = b1[tid];
        float h0 = fmaxf((y0 - mean0) * rsqrtf(var0 + EPS_LN) * gg + bb, 0.f);
        float h1 = fmaxf((y1 - mean1) * rsqrtf(var1 + EPS_LN) * gg + bb, 0.f);
        r0 = x[(size_t)(row0 + 0) * HID + tid] + h0;
        r1 = x[(size_t)(row0 + 1) * HID + tid] + h1;
    }

    {
        float s0 = r0, q0 = r0 * r0, s1 = r1, q1 = r1 * r1;
        #pragma unroll
        for (int d = 1; d < 64; d <<= 1) {
            s0 += __shfl_xor(s0, d, 64); q0 += __shfl_xor(q0, d, 64);
            s1 += __shfl_xor(s1, d, 64); q1 += __shfl_xor(q1, d, 64);
        }
        if ((tid & 63) == 0) {
            int w = tid >> 6;
            st[0][w][0] = s0; st[0][w][1] = q0;
            st[1][w][0] = s1; st[1][w][1] = q1;
        }
    }
    __syncthreads();
    mean0 = (st[0][0][0] + st[0][1][0]) * (1.0f / HID);
    var0  = (st[0][0][1] + st[0][1][1]) * (1.0f / HID) - mean0 * mean0;
    mean1 = (st[1][0][0] + st[1][1][0]) * (1.0f / HID);
    var1  = (st[1][0][1] + st[1][1][1]) * (1.0f / HID) - mean1 * mean1;

    if (tid < HID) {
        out[(size_t)(row0 + 0) * HID + tid] =
            (r0 - mean0) * rsqrtf(var0 + EPS_LN) * g2[tid] + b2[tid];
        out[(size_t)(row0 + 1) * HID + tid] =
            (r1 - mean1) * rsqrtf(var1 + EPS_LN) * g2[tid] + b2[tid];
    }
}

// ============================================================ launch
extern "C" void kernel_launch(void* const* d_in, const int* in_sizes, int n_in,
                              void* d_out, int out_size, void* d_ws, size_t ws_size,
                              hipStream_t stream)
{
    const float* x      = (const float*)d_in[0];
    const float* pos_CA = (const float*)d_in[1];
    const float* pos_CB = (const float*)d_in[2];
    const float* Wq = (const float*)d_in[4],  *bq = (const float*)d_in[5];
    const float* Wk = (const float*)d_in[6],  *bk = (const float*)d_in[7];
    const float* Wv = (const float*)d_in[8],  *bv = (const float*)d_in[9];
    const float* Wo = (const float*)d_in[10], *bo = (const float*)d_in[11];
    const float* g1 = (const float*)d_in[12], *b1 = (const float*)d_in[13];
    const float* g2 = (const float*)d_in[14], *b2 = (const float*)d_in[15];
    float* out = (float*)d_out;

    const size_t FR = 524288;                 // ushorts per frag array (1 MB)
    unsigned short* khi = (unsigned short*)d_ws;
    unsigned short* qhi = khi + FR;
    unsigned short* qlo = khi + 2 * FR;
    unsigned short* vfr = khi + 3 * FR;
    const size_t FRAG_BYTES = 4 * FR * 2;     // 4 MB
    float* part = (float*)((char*)d_ws + FRAG_BYTES);   // 33.6 MB
    const size_t PART_BYTES = (size_t)8 * 128 * NSPLIT * 16 * 32 * 4;
    unsigned short* wf = (unsigned short*)((char*)d_ws + FRAG_BYTES + PART_BYTES);

    hipLaunchKernelGGL(wpack_kernel, dim3(54), dim3(64), 0, stream, Wq, Wk, Wv, wf);
    hipLaunchKernelGGL(qkvfrag_kernel, dim3(256 * 3), dim3(64), 0, stream,
                       x, pos_CA, bq, bk, bv, wf, khi, qhi, qlo, vfr);
    int nblocks = (8 * 32 * NSPLIT) / 4;      // 4096 wave-tasks, 4 waves/block
    hipLaunchKernelGGL(attn_mfma_kernel, dim3(nblocks), dim3(256), 0, stream,
                       khi, qhi, qlo, vfr, part);
    hipLaunchKernelGGL(finalize_kernel, dim3(NROWS / 2), dim3(128), 0, stream,
                       part, pos_CA, pos_CB, x, Wo, bo, g1, b1, g2, b2, out);
}

// Round 14
// 56.827 us; speedup vs baseline: 1.0487x; 1.0487x over previous
//
#include <hip/hip_runtime.h>

#define HID 96
#define NHEADS 4
#define FEAT 124
#define EPS_LN 1e-5f
#define NROWS 4096          // B*N
#define NB 2048             // N per batch
#define NSPLIT 16

typedef __attribute__((ext_vector_type(8))) short bf16x8;
typedef __attribute__((ext_vector_type(4))) float f32x4;
typedef __attribute__((ext_vector_type(2))) unsigned int uint2v;

__device__ __forceinline__ unsigned short f2bf(float x) {
    unsigned int u = __float_as_uint(x);
    unsigned int r = (u + 0x7FFFu + ((u >> 16) & 1u)) >> 16;
    return (unsigned short)r;
}
__device__ __forceinline__ float bf2f(unsigned short h) {
    return __uint_as_float(((unsigned int)h) << 16);
}

// ============================================================ W fragment pack
__global__ __launch_bounds__(64) void wpack_kernel(
    const float* __restrict__ Wq, const float* __restrict__ Wk,
    const float* __restrict__ Wv, unsigned short* __restrict__ wf)
{
    int bid = blockIdx.x;
    int mat = bid / 18, kc = (bid / 6) % 3, jt = bid % 6;
    int lane = threadIdx.x;
    const float* W = (mat == 0) ? Wq : (mat == 1) ? Wk : Wv;
    int j = jt * 16 + (lane & 15);
    int t0 = kc * 32 + (lane >> 4) * 8;
    bf16x8 hi, lo;
    #pragma unroll
    for (int e = 0; e < 8; ++e) {
        float v = W[(t0 + e) * HID + j];
        unsigned short h = f2bf(v);
        hi[e] = (short)h;
        lo[e] = (short)f2bf(v - bf2f(h));
    }
    *(bf16x8*)(wf + ((size_t)(bid * 2 + 0) * 64 + lane) * 8) = hi;
    *(bf16x8*)(wf + ((size_t)(bid * 2 + 1) * 64 + lane) * 8) = lo;
}

// ============================================================ QKV via MFMA
// k stores hi only (the kl*qh QK term is dropped; see attn kernel).
__global__ __launch_bounds__(64) void qkvfrag_kernel(
    const float* __restrict__ x, const float* __restrict__ pos_CA,
    const float* __restrict__ bq, const float* __restrict__ bk,
    const float* __restrict__ bv, const unsigned short* __restrict__ wf,
    unsigned short* __restrict__ khi,
    unsigned short* __restrict__ qhi, unsigned short* __restrict__ qlo,
    unsigned short* __restrict__ vfr)
{
    int nt = blockIdx.x / 3, mat = blockIdx.x % 3;
    int lane = threadIdx.x;
    int row0 = nt * 16;
    int b = row0 >> 11;
    int ntb = nt & 127;                 // per-batch 16-row tile
    int T = ntb >> 1;                   // per-batch 32-row tile
    __shared__ float xs[16][97];
    for (int i = lane; i < 16 * HID; i += 64)
        xs[i / HID][i % HID] = x[(size_t)row0 * HID + i];
    __syncthreads();

    int n = lane & 15, g = lane >> 4;
    bf16x8 xh[3], xl[3];
    #pragma unroll
    for (int kc = 0; kc < 3; ++kc)
        #pragma unroll
        for (int e = 0; e < 8; ++e) {
            float v = xs[n][kc * 32 + g * 8 + e];
            unsigned short h = f2bf(v);
            xh[kc][e] = (short)h;
            xl[kc][e] = (short)f2bf(v - bf2f(h));
        }

    const float* bias = (mat == 0) ? bq : (mat == 1) ? bk : bv;

    #pragma unroll
    for (int jt = 0; jt < 6; ++jt) {
        f32x4 acc;
        #pragma unroll
        for (int r = 0; r < 4; ++r) acc[r] = bias[jt * 16 + 4 * g + r];
        #pragma unroll
        for (int kc = 0; kc < 3; ++kc) {
            const unsigned short* A = wf + (size_t)(((mat * 3 + kc) * 6 + jt) * 2) * 512;
            bf16x8 ah = *(const bf16x8*)(A + lane * 8);
            bf16x8 al = *(const bf16x8*)(A + 512 + lane * 8);
            acc = __builtin_amdgcn_mfma_f32_16x16x32_bf16(ah, xh[kc], acc, 0, 0, 0);
            acc = __builtin_amdgcn_mfma_f32_16x16x32_bf16(al, xh[kc], acc, 0, 0, 0);
            acc = __builtin_amdgcn_mfma_f32_16x16x32_bf16(ah, xl[kc], acc, 0, 0, 0);
        }
        if (mat < 2) {
            int jg0 = jt * 16 + 4 * g;
            int h = jg0 / 24;
            int d0 = jg0 - 24 * h;
            int bh = b * NHEADS + h;
            size_t base = ((size_t)(bh * 128 + ntb) * 64 + n + 16 * (d0 >> 3)) * 8 + (d0 & 7);
            unsigned short h0 = f2bf(acc[0]), h1 = f2bf(acc[1]);
            unsigned short h2 = f2bf(acc[2]), h3 = f2bf(acc[3]);
            uint2v hv = { (unsigned int)h0 | ((unsigned int)h1 << 16),
                          (unsigned int)h2 | ((unsigned int)h3 << 16) };
            if (mat == 0) {
                *(uint2v*)(qhi + base) = hv;
                unsigned short l0 = f2bf(acc[0] - bf2f(h0)), l1 = f2bf(acc[1] - bf2f(h1));
                unsigned short l2 = f2bf(acc[2] - bf2f(h2)), l3 = f2bf(acc[3] - bf2f(h3));
                uint2v lv = { (unsigned int)l0 | ((unsigned int)l1 << 16),
                              (unsigned int)l2 | ((unsigned int)l3 << 16) };
                *(uint2v*)(qlo + base) = lv;
            } else {
                *(uint2v*)(khi + base) = hv;
            }
        } else {
            int g2 = (ntb & 1) * 2 + (n >> 3);
            #pragma unroll
            for (int r = 0; r < 4; ++r) {
                int jg = jt * 16 + 4 * g + r;
                int h = jg / 24;
                int d = jg - 24 * h;
                int bh = b * NHEADS + h;
                size_t vidx = (((size_t)(bh * 64 + T) * 2 + (d >> 4)) * 64
                               + (d & 15) + 16 * g2) * 8 + (n & 7);
                vfr[vidx] = f2bf(acc[r]);
            }
        }
    }

    if (mat == 2) {
        {
            int h = g;
            int bh = b * NHEADS + h;
            size_t fi = ((size_t)(bh * 128 + ntb) * 64 + 48 + n) * 8;
            bf16x8 zz = {0, 0, 0, 0, 0, 0, 0, 0};
            *(bf16x8*)(khi + fi) = zz;
            *(bf16x8*)(qhi + fi) = zz;
            *(bf16x8*)(qlo + fi) = zz;
        }
        if (lane < 4) {
            int col = 14 + (lane & 1);
            int g2 = (ntb & 1) * 2 + (lane >> 1);
            bf16x8 zz = {0, 0, 0, 0, 0, 0, 0, 0};
            #pragma unroll
            for (int h = 0; h < NHEADS; ++h) {
                int bh = b * NHEADS + h;
                *(bf16x8*)(vfr + (((size_t)(bh * 64 + T) * 2 + 1) * 64 + col + 16 * g2) * 8) = zz;
            }
        }
        {
            int row = row0 + n;
            int h = g;
            int bh = b * NHEADS + h;
            int g2 = (ntb & 1) * 2 + (n >> 3);
            #pragma unroll
            for (int rem = 0; rem < 6; ++rem) {
                int c = rem % 3;
                bool ishi = rem < 3;
                float val = pos_CA[(size_t)row * 3 + c];
                unsigned short hv = f2bf(val);
                unsigned short sv = ishi ? hv : f2bf(val - bf2f(hv));
                int col = (ishi ? 8 : 11) + c;
                vfr[(((size_t)(bh * 64 + T) * 2 + 1) * 64 + col + 16 * g2) * 8 + (n & 7)] = sv;
            }
        }
    }
}

// ============================================================ MFMA flash attention
// r11 structure (2 q-tiles/wave, 8192 waves = 8/SIMD) + s_setprio around the
// MFMA clusters (T5: waves are barrier-free and phase-diverse, so priority
// keeps the matrix pipe fed while sibling waves run exp/LDS/loads).
__global__ __launch_bounds__(256) void attn_mfma_kernel(
    const unsigned short* __restrict__ khi,
    const unsigned short* __restrict__ qhi, const unsigned short* __restrict__ qlo,
    const unsigned short* __restrict__ vfr,
    float* __restrict__ part)
{
    __shared__ unsigned short pfrag[4][2][2][64][8];   // [wave][qt][ktile][lane][j]
    int wid = threadIdx.x >> 6;
    int lane = threadIdx.x & 63;
    int task = blockIdx.x * 4 + wid;
    int qtp = task & 63;
    int bh = (task >> 6) & 7;
    int ks = task >> 9;
    int qcol = lane & 15, g = lane >> 4;

    bf16x8 qh2[2], ql2[2];
    #pragma unroll
    for (int qi2 = 0; qi2 < 2; ++qi2) {
        int qt = qtp * 2 + qi2;
        qh2[qi2] = *(const bf16x8*)(qhi + ((size_t)(bh * 128 + qt) * 64 + lane) * 8);
        ql2[qi2] = *(const bf16x8*)(qlo + ((size_t)(bh * 128 + qt) * 64 + lane) * 8);
    }

    f32x4 z = {0.f, 0.f, 0.f, 0.f};
    f32x4 acc[2][2] = {{z, z}, {z, z}};
    float ll[2] = {0.f, 0.f};

    #pragma unroll
    for (int t8 = 0; t8 < 32 / NSPLIT; ++t8) {
        int kt0 = ks * (128 / NSPLIT) + t8 * 4;
        const unsigned short* kb = khi + ((size_t)(bh * 128 + kt0) * 64 + lane) * 8;
        bf16x8 kh[4];
        #pragma unroll
        for (int i = 0; i < 4; ++i)
            kh[i] = *(const bf16x8*)(kb + i * 512);
        int T0 = ks * (64 / NSPLIT) + t8 * 2;
        const unsigned short* vb = vfr + ((size_t)(bh * 64 + T0) * 2 * 64 + lane) * 8;
        bf16x8 v00 = *(const bf16x8*)(vb);
        bf16x8 v01 = *(const bf16x8*)(vb + 512);
        bf16x8 v10 = *(const bf16x8*)(vb + 1024);
        bf16x8 v11 = *(const bf16x8*)(vb + 1536);

        #pragma unroll
        for (int qi2 = 0; qi2 < 2; ++qi2) {
            f32x4 s[4];
            __builtin_amdgcn_s_setprio(1);
            #pragma unroll
            for (int i = 0; i < 4; ++i) {
                s[i] = __builtin_amdgcn_mfma_f32_16x16x32_bf16(kh[i], qh2[qi2], z, 0, 0, 0);
                s[i] = __builtin_amdgcn_mfma_f32_16x16x32_bf16(kh[i], ql2[qi2], s[i], 0, 0, 0);
            }
            __builtin_amdgcn_s_setprio(0);
            float p[4][4];
            float ts = 0.f;
            #pragma unroll
            for (int i = 0; i < 4; ++i)
                #pragma unroll
                for (int r = 0; r < 4; ++r) {
                    float pv = __expf(s[i][r]);
                    p[i][r] = pv;
                    ts += pv;
                }
            ts += __shfl_xor(ts, 16, 64);
            ts += __shfl_xor(ts, 32, 64);
            ll[qi2] += ts;

            #pragma unroll
            for (int t = 0; t < 4; ++t) {
                int lp = qcol + 16 * (2 * (t & 1) + (g >> 1));
                unsigned int w0, w1;
                asm("v_cvt_pk_bf16_f32 %0, %1, %2" : "=v"(w0) : "v"(p[t][0]), "v"(p[t][1]));
                asm("v_cvt_pk_bf16_f32 %0, %1, %2" : "=v"(w1) : "v"(p[t][2]), "v"(p[t][3]));
                unsigned int* dst = (unsigned int*)&pfrag[wid][qi2][t >> 1][lp][(g & 1) * 4];
                dst[0] = w0; dst[1] = w1;
            }
            bf16x8 pf0 = *(const bf16x8*)&pfrag[wid][qi2][0][lane][0];
            bf16x8 pf1 = *(const bf16x8*)&pfrag[wid][qi2][1][lane][0];

            __builtin_amdgcn_s_setprio(1);
            acc[qi2][0] = __builtin_amdgcn_mfma_f32_16x16x32_bf16(v00, pf0, acc[qi2][0], 0, 0, 0);
            acc[qi2][0] = __builtin_amdgcn_mfma_f32_16x16x32_bf16(v10, pf1, acc[qi2][0], 0, 0, 0);
            acc[qi2][1] = __builtin_amdgcn_mfma_f32_16x16x32_bf16(v01, pf0, acc[qi2][1], 0, 0, 0);
            acc[qi2][1] = __builtin_amdgcn_mfma_f32_16x16x32_bf16(v11, pf1, acc[qi2][1], 0, 0, 0);
            __builtin_amdgcn_s_setprio(0);
        }
    }

    // partial: [bh][qt][ks][qrow 16][32]: 0..29 acc(vd), 30 l
    #pragma unroll
    for (int qi2 = 0; qi2 < 2; ++qi2) {
        int qt = qtp * 2 + qi2;
        float* pp = part + ((size_t)((bh * 128 + qt) * NSPLIT + ks) * 16 + qcol) * 32;
        #pragma unroll
        for (int r = 0; r < 4; ++r) pp[g * 4 + r] = acc[qi2][0][r];
        if (g < 3) {
            #pragma unroll
            for (int r = 0; r < 4; ++r) pp[16 + g * 4 + r] = acc[qi2][1][r];
        } else {
            pp[28] = acc[qi2][1][0];
            pp[29] = acc[qi2][1][1];
            pp[30] = ll[qi2];
        }
    }
}

// ============================================================ combine + finalize
__global__ __launch_bounds__(128) void finalize_kernel(
    const float* __restrict__ part,
    const float* __restrict__ pos_CA, const float* __restrict__ pos_CB,
    const float* __restrict__ x,
    const float* __restrict__ Wo, const float* __restrict__ bo,
    const float* __restrict__ g1, const float* __restrict__ b1,
    const float* __restrict__ g2, const float* __restrict__ b2,
    float* __restrict__ out)
{
    int row0 = blockIdx.x * 2;
    int tid = threadIdx.x;
    __shared__ float fsL[2][FEAT];
    __shared__ float cawS[2][NHEADS][3];
    __shared__ float st[2][2][2];

    #pragma unroll
    for (int it = 0; it < 2; ++it) {
        int T = tid + it * 128;
        if (T < 240) {
            int r = T / 120, u = T % 120;
            int h = u / 30, vd = u % 30;
            int row = row0 + r;
            int b = row >> 11, n = row & (NB - 1);
            int bh = b * NHEADS + h;
            const float* pb = part + ((size_t)((bh * 128 + (n >> 4)) * NSPLIT) * 16 + (n & 15)) * 32;
            float A = 0.f, L = 0.f, A2 = 0.f;
            #pragma unroll 4
            for (int ks = 0; ks < NSPLIT; ++ks) {
                const float* pk = pb + ks * (16 * 32);
                A += pk[vd];
                L += pk[30];
                if (vd >= 24 && vd < 27) A2 += pk[vd + 3];
            }
            if (vd < 24) fsL[r][h * 24 + vd] = A / L;
            else if (vd < 27) cawS[r][h][vd - 24] = (A + A2) / L;
        }
    }
    __syncthreads();

    if (tid >= 96 && tid < 104) {
        int i2 = tid - 96;
        int r = i2 >> 2, h = i2 & 3;
        int row = row0 + r;
        int n = row & (NB - 1);
        float cax = pos_CA[(size_t)row * 3 + 0];
        float cay = pos_CA[(size_t)row * 3 + 1];
        float caz = pos_CA[(size_t)row * 3 + 2];
        float cbx = pos_CB[(size_t)row * 3 + 0];
        float cby = pos_CB[(size_t)row * 3 + 1];
        float cbz = pos_CB[(size_t)row * 3 + 2];
        float e1x = cbx - cax, e1y = cby - cay, e1z = cbz - caz;
        float n1 = sqrtf(e1x * e1x + e1y * e1y + e1z * e1z);
        bool valid1 = n1 > 1e-6f;
        float inv1 = 1.f / fmaxf(n1, 1e-12f);
        float ax = e1x * inv1, ay = e1y * inv1, az = e1z * inv1;
        float e2x = ay, e2y = -ax, e2z = 0.f;
        float n2a = sqrtf(e2x * e2x + e2y * e2y);
        if (n2a < 1e-6f) { e2x = -az; e2y = 0.f; e2z = ax; }
        float n2 = sqrtf(e2x * e2x + e2y * e2y + e2z * e2z);
        bool valid2 = n2 > 1e-6f;
        float inv2 = 1.f / fmaxf(n2, 1e-12f);
        float bx = e2x * inv2, by = e2y * inv2, bz = e2z * inv2;
        float cx = ay * bz - az * by;
        float cy = az * bx - ax * bz;
        float cz = ax * by - ay * bx;
        bool valid = valid1 && valid2 && (n < NB - 1);
        float F00, F01, F02, F10, F11, F12, F20, F21, F22;
        if (valid) { F00 = ax; F10 = ay; F20 = az;
                     F01 = bx; F11 = by; F21 = bz;
                     F02 = cx; F12 = cy; F22 = cz; }
        else { F00 = 1.f; F01 = 0.f; F02 = 0.f;
               F10 = 0.f; F11 = 1.f; F12 = 0.f;
               F20 = 0.f; F21 = 0.f; F22 = 1.f; }
        float b0 = cbx - cawS[r][h][0];
        float b1v = cby - cawS[r][h][1];
        float b2v = cbz - cawS[r][h][2];
        float dist = sqrtf(b0 * b0 + b1v * b1v + b2v * b2v);
        float p0 = F00 * b0 + F01 * b1v + F02 * b2v;
        float p1 = F10 * b0 + F11 * b1v + F12 * b2v;
        float p2 = F20 * b0 + F21 * b1v + F22 * b2v;
        float pn = sqrtf(p0 * p0 + p1 * p1 + p2 * p2);
        float invp = 1.f / (pn + 1e-10f);
        fsL[r][HID + h * 3 + 0] = p0;
        fsL[r][HID + h * 3 + 1] = p1;
        fsL[r][HID + h * 3 + 2] = p2;
        fsL[r][HID + 12 + h] = dist;
        fsL[r][HID + 16 + h * 3 + 0] = p0 * invp;
        fsL[r][HID + 16 + h * 3 + 1] = p1 * invp;
        fsL[r][HID + 16 + h * 3 + 2] = p2 * invp;
    }
    __syncthreads();

    float y0 = 0.f, y1 = 0.f;
    if (tid < HID) {
        float bj = bo[tid];
        y0 = bj; y1 = bj;
        #pragma unroll 4
        for (int i = 0; i < FEAT; ++i) {
            float w = Wo[i * HID + tid];
            y0 = fmaf(fsL[0][i], w, y0);
            y1 = fmaf(fsL[1][i], w, y1);
        }
    }

    {
        float s0 = y0, q0 = y0 * y0, s1 = y1, q1 = y1 * y1;
        #pragma unroll
        for (int d = 1; d < 64; d <<= 1) {
            s0 += __shfl_xor(s0, d, 64); q0 += __shfl_xor(q0, d, 64);
            s1 += __shfl_xor(s1, d, 64); q1 += __shfl_xor(q1, d, 64);
        }
        if ((tid & 63) == 0) {
            int w = tid >> 6;
            st[0][w][0] = s0; st[0][w][1] = q0;
            st[1][w][0] = s1; st[1][w][1] = q1;
        }
    }
    __syncthreads();
    float mean0 = (st[0][0][0] + st[0][1][0]) * (1.0f / HID);
    float var0  = (st[0][0][1] + st[0][1][1]) * (1.0f / HID) - mean0 * mean0;
    float mean1 = (st[1][0][0] + st[1][1][0]) * (1.0f / HID);
    float var1  = (st[1][0][1] + st[1][1][1]) * (1.0f / HID) - mean1 * mean1;
    __syncthreads();

    float r0 = 0.f, r1 = 0.f;
    if (tid < HID) {
        float gg = g1[tid], bb = b1[tid];
        float h0 = fmaxf((y0 - mean0) * rsqrtf(var0 + EPS_LN) * gg + bb, 0.f);
        float h1 = fmaxf((y1 - mean1) * rsqrtf(var1 + EPS_LN) * gg + bb, 0.f);
        r0 = x[(size_t)(row0 + 0) * HID + tid] + h0;
        r1 = x[(size_t)(row0 + 1) * HID + tid] + h1;
    }

    {
        float s0 = r0, q0 = r0 * r0, s1 = r1, q1 = r1 * r1;
        #pragma unroll
        for (int d = 1; d < 64; d <<= 1) {
            s0 += __shfl_xor(s0, d, 64); q0 += __shfl_xor(q0, d, 64);
            s1 += __shfl_xor(s1, d, 64); q1 += __shfl_xor(q1, d, 64);
        }
        if ((tid & 63) == 0) {
            int w = tid >> 6;
            st[0][w][0] = s0; st[0][w][1] = q0;
            st[1][w][0] = s1; st[1][w][1] = q1;
        }
    }
    __syncthreads();
    mean0 = (st[0][0][0] + st[0][1][0]) * (1.0f / HID);
    var0  = (st[0][0][1] + st[0][1][1]) * (1.0f / HID) - mean0 * mean0;
    mean1 = (st[1][0][0] + st[1][1][0]) * (1.0f / HID);
    var1  = (st[1][0][1] + st[1][1][1]) * (1.0f / HID) - mean1 * mean1;

    if (tid < HID) {
        out[(size_t)(row0 + 0) * HID + tid] =
            (r0 - mean0) * rsqrtf(var0 + EPS_LN) * g2[tid] + b2[tid];
        out[(size_t)(row0 + 1) * HID + tid] =
            (r1 - mean1) * rsqrtf(var1 + EPS_LN) * g2[tid] + b2[tid];
    }
}

// ============================================================ launch
extern "C" void kernel_launch(void* const* d_in, const int* in_sizes, int n_in,
                              void* d_out, int out_size, void* d_ws, size_t ws_size,
                              hipStream_t stream)
{
    const float* x      = (const float*)d_in[0];
    const float* pos_CA = (const float*)d_in[1];
    const float* pos_CB = (const float*)d_in[2];
    const float* Wq = (const float*)d_in[4],  *bq = (const float*)d_in[5];
    const float* Wk = (const float*)d_in[6],  *bk = (const float*)d_in[7];
    const float* Wv = (const float*)d_in[8],  *bv = (const float*)d_in[9];
    const float* Wo = (const float*)d_in[10], *bo = (const float*)d_in[11];
    const float* g1 = (const float*)d_in[12], *b1 = (const float*)d_in[13];
    const float* g2 = (const float*)d_in[14], *b2 = (const float*)d_in[15];
    float* out = (float*)d_out;

    const size_t FR = 524288;                 // ushorts per frag array (1 MB)
    unsigned short* khi = (unsigned short*)d_ws;
    unsigned short* qhi = khi + FR;
    unsigned short* qlo = khi + 2 * FR;
    unsigned short* vfr = khi + 3 * FR;
    const size_t FRAG_BYTES = 4 * FR * 2;     // 4 MB
    float* part = (float*)((char*)d_ws + FRAG_BYTES);   // 33.6 MB
    const size_t PART_BYTES = (size_t)8 * 128 * NSPLIT * 16 * 32 * 4;
    unsigned short* wf = (unsigned short*)((char*)d_ws + FRAG_BYTES + PART_BYTES);

    hipLaunchKernelGGL(wpack_kernel, dim3(54), dim3(64), 0, stream, Wq, Wk, Wv, wf);
    hipLaunchKernelGGL(qkvfrag_kernel, dim3(256 * 3), dim3(64), 0, stream,
                       x, pos_CA, bq, bk, bv, wf, khi, qhi, qlo, vfr);
    int nblocks = (8 * 64 * NSPLIT) / 4;      // 8192 wave-tasks, 4 waves/block
    hipLaunchKernelGGL(attn_mfma_kernel, dim3(nblocks), dim3(256), 0, stream,
                       khi, qhi, qlo, vfr, part);
    hipLaunchKernelGGL(finalize_kernel, dim3(NROWS / 2), dim3(128), 0, stream,
                       part, pos_CA, pos_CB, x, Wo, bo, g1, b1, g2, b2, out);
}

// Round 16
// 53.044 us; speedup vs baseline: 1.1235x; 1.0713x over previous
//
#include <hip/hip_runtime.h>

#define HID 96
#define NHEADS 4
#define FEAT 124
#define EPS_LN 1e-5f
#define NROWS 4096          // B*N
#define NB 2048             // N per batch
#define NSPLIT 16

typedef __attribute__((ext_vector_type(8))) short bf16x8;
typedef __attribute__((ext_vector_type(4))) float f32x4;
typedef __attribute__((ext_vector_type(2))) unsigned int uint2v;

__device__ __forceinline__ unsigned short f2bf(float x) {
    unsigned int u = __float_as_uint(x);
    unsigned int r = (u + 0x7FFFu + ((u >> 16) & 1u)) >> 16;
    return (unsigned short)r;
}
__device__ __forceinline__ float bf2f(unsigned short h) {
    return __uint_as_float(((unsigned int)h) << 16);
}

// ============================================================ QKV via MFMA
// wpack merged in: each lane converts its own W slice inline (bit-identical
// to the old wf fragments — same index algebra, same f2bf split).
// k stores hi only (kl*qh QK term dropped; see attn kernel).
__global__ __launch_bounds__(64) void qkvfrag_kernel(
    const float* __restrict__ x, const float* __restrict__ pos_CA,
    const float* __restrict__ Wq, const float* __restrict__ bq,
    const float* __restrict__ Wk, const float* __restrict__ bk,
    const float* __restrict__ Wv, const float* __restrict__ bv,
    unsigned short* __restrict__ khi,
    unsigned short* __restrict__ qhi, unsigned short* __restrict__ qlo,
    unsigned short* __restrict__ vfr)
{
    int nt = blockIdx.x / 3, mat = blockIdx.x % 3;
    int lane = threadIdx.x;
    int row0 = nt * 16;
    int b = row0 >> 11;
    int ntb = nt & 127;                 // per-batch 16-row tile
    int T = ntb >> 1;                   // per-batch 32-row tile
    __shared__ float xs[16][97];
    for (int i = lane; i < 16 * HID; i += 64)
        xs[i / HID][i % HID] = x[(size_t)row0 * HID + i];
    __syncthreads();

    int n = lane & 15, g = lane >> 4;
    bf16x8 xh[3], xl[3];
    #pragma unroll
    for (int kc = 0; kc < 3; ++kc)
        #pragma unroll
        for (int e = 0; e < 8; ++e) {
            float v = xs[n][kc * 32 + g * 8 + e];
            unsigned short h = f2bf(v);
            xh[kc][e] = (short)h;
            xl[kc][e] = (short)f2bf(v - bf2f(h));
        }

    const float* bias = (mat == 0) ? bq : (mat == 1) ? bk : bv;
    const float* W    = (mat == 0) ? Wq : (mat == 1) ? Wk : Wv;
    int wj = lane & 15;
    int wt0 = (lane >> 4) * 8;

    #pragma unroll
    for (int jt = 0; jt < 6; ++jt) {
        f32x4 acc;
        #pragma unroll
        for (int r = 0; r < 4; ++r) acc[r] = bias[jt * 16 + 4 * g + r];
        #pragma unroll
        for (int kc = 0; kc < 3; ++kc) {
            bf16x8 ah, al;                    // inline wpack (bit-identical)
            #pragma unroll
            for (int e = 0; e < 8; ++e) {
                float wv = W[(kc * 32 + wt0 + e) * HID + jt * 16 + wj];
                unsigned short h = f2bf(wv);
                ah[e] = (short)h;
                al[e] = (short)f2bf(wv - bf2f(h));
            }
            acc = __builtin_amdgcn_mfma_f32_16x16x32_bf16(ah, xh[kc], acc, 0, 0, 0);
            acc = __builtin_amdgcn_mfma_f32_16x16x32_bf16(al, xh[kc], acc, 0, 0, 0);
            acc = __builtin_amdgcn_mfma_f32_16x16x32_bf16(ah, xl[kc], acc, 0, 0, 0);
        }
        if (mat < 2) {
            int jg0 = jt * 16 + 4 * g;
            int h = jg0 / 24;
            int d0 = jg0 - 24 * h;
            int bh = b * NHEADS + h;
            size_t base = ((size_t)(bh * 128 + ntb) * 64 + n + 16 * (d0 >> 3)) * 8 + (d0 & 7);
            unsigned short h0 = f2bf(acc[0]), h1 = f2bf(acc[1]);
            unsigned short h2 = f2bf(acc[2]), h3 = f2bf(acc[3]);
            uint2v hv = { (unsigned int)h0 | ((unsigned int)h1 << 16),
                          (unsigned int)h2 | ((unsigned int)h3 << 16) };
            if (mat == 0) {
                *(uint2v*)(qhi + base) = hv;
                unsigned short l0 = f2bf(acc[0] - bf2f(h0)), l1 = f2bf(acc[1] - bf2f(h1));
                unsigned short l2 = f2bf(acc[2] - bf2f(h2)), l3 = f2bf(acc[3] - bf2f(h3));
                uint2v lv = { (unsigned int)l0 | ((unsigned int)l1 << 16),
                              (unsigned int)l2 | ((unsigned int)l3 << 16) };
                *(uint2v*)(qlo + base) = lv;
            } else {
                *(uint2v*)(khi + base) = hv;
            }
        } else {
            int g2 = (ntb & 1) * 2 + (n >> 3);
            #pragma unroll
            for (int r = 0; r < 4; ++r) {
                int jg = jt * 16 + 4 * g + r;
                int h = jg / 24;
                int d = jg - 24 * h;
                int bh = b * NHEADS + h;
                size_t vidx = (((size_t)(bh * 64 + T) * 2 + (d >> 4)) * 64
                               + (d & 15) + 16 * g2) * 8 + (n & 7);
                vfr[vidx] = f2bf(acc[r]);
            }
        }
    }

    if (mat == 2) {
        {
            int h = g;
            int bh = b * NHEADS + h;
            size_t fi = ((size_t)(bh * 128 + ntb) * 64 + 48 + n) * 8;
            bf16x8 zz = {0, 0, 0, 0, 0, 0, 0, 0};
            *(bf16x8*)(khi + fi) = zz;
            *(bf16x8*)(qhi + fi) = zz;
            *(bf16x8*)(qlo + fi) = zz;
        }
        if (lane < 4) {
            int col = 14 + (lane & 1);
            int g2 = (ntb & 1) * 2 + (lane >> 1);
            bf16x8 zz = {0, 0, 0, 0, 0, 0, 0, 0};
            #pragma unroll
            for (int h = 0; h < NHEADS; ++h) {
                int bh = b * NHEADS + h;
                *(bf16x8*)(vfr + (((size_t)(bh * 64 + T) * 2 + 1) * 64 + col + 16 * g2) * 8) = zz;
            }
        }
        {
            int row = row0 + n;
            int h = g;
            int bh = b * NHEADS + h;
            int g2 = (ntb & 1) * 2 + (n >> 3);
            #pragma unroll
            for (int rem = 0; rem < 6; ++rem) {
                int c = rem % 3;
                bool ishi = rem < 3;
                float val = pos_CA[(size_t)row * 3 + c];
                unsigned short hv = f2bf(val);
                unsigned short sv = ishi ? hv : f2bf(val - bf2f(hv));
                int col = (ishi ? 8 : 11) + c;
                vfr[(((size_t)(bh * 64 + T) * 2 + 1) * 64 + col + 16 * g2) * 8 + (n & 7)] = sv;
            }
        }
    }
}

// ============================================================ MFMA flash attention
// r11 structure: 2 q-tiles/wave, 8192 waves (8/SIMD), no barriers.
// S = kh*(qh+ql). Fixed-shift softmax (m=0). Partials (30 accs + l) stride 32.
__global__ __launch_bounds__(256) void attn_mfma_kernel(
    const unsigned short* __restrict__ khi,
    const unsigned short* __restrict__ qhi, const unsigned short* __restrict__ qlo,
    const unsigned short* __restrict__ vfr,
    float* __restrict__ part)
{
    __shared__ unsigned short pfrag[4][2][2][64][8];   // [wave][qt][ktile][lane][j]
    int wid = threadIdx.x >> 6;
    int lane = threadIdx.x & 63;
    int task = blockIdx.x * 4 + wid;
    int qtp = task & 63;
    int bh = (task >> 6) & 7;
    int ks = task >> 9;
    int qcol = lane & 15, g = lane >> 4;

    bf16x8 qh2[2], ql2[2];
    #pragma unroll
    for (int qi2 = 0; qi2 < 2; ++qi2) {
        int qt = qtp * 2 + qi2;
        qh2[qi2] = *(const bf16x8*)(qhi + ((size_t)(bh * 128 + qt) * 64 + lane) * 8);
        ql2[qi2] = *(const bf16x8*)(qlo + ((size_t)(bh * 128 + qt) * 64 + lane) * 8);
    }

    f32x4 z = {0.f, 0.f, 0.f, 0.f};
    f32x4 acc[2][2] = {{z, z}, {z, z}};
    float ll[2] = {0.f, 0.f};

    #pragma unroll
    for (int t8 = 0; t8 < 32 / NSPLIT; ++t8) {
        int kt0 = ks * (128 / NSPLIT) + t8 * 4;
        const unsigned short* kb = khi + ((size_t)(bh * 128 + kt0) * 64 + lane) * 8;
        bf16x8 kh[4];
        #pragma unroll
        for (int i = 0; i < 4; ++i)
            kh[i] = *(const bf16x8*)(kb + i * 512);
        int T0 = ks * (64 / NSPLIT) + t8 * 2;
        const unsigned short* vb = vfr + ((size_t)(bh * 64 + T0) * 2 * 64 + lane) * 8;
        bf16x8 v00 = *(const bf16x8*)(vb);
        bf16x8 v01 = *(const bf16x8*)(vb + 512);
        bf16x8 v10 = *(const bf16x8*)(vb + 1024);
        bf16x8 v11 = *(const bf16x8*)(vb + 1536);

        #pragma unroll
        for (int qi2 = 0; qi2 < 2; ++qi2) {
            f32x4 s[4];
            #pragma unroll
            for (int i = 0; i < 4; ++i) {
                s[i] = __builtin_amdgcn_mfma_f32_16x16x32_bf16(kh[i], qh2[qi2], z, 0, 0, 0);
                s[i] = __builtin_amdgcn_mfma_f32_16x16x32_bf16(kh[i], ql2[qi2], s[i], 0, 0, 0);
            }
            float p[4][4];
            float ts = 0.f;
            #pragma unroll
            for (int i = 0; i < 4; ++i)
                #pragma unroll
                for (int r = 0; r < 4; ++r) {
                    float pv = __expf(s[i][r]);
                    p[i][r] = pv;
                    ts += pv;
                }
            ts += __shfl_xor(ts, 16, 64);
            ts += __shfl_xor(ts, 32, 64);
            ll[qi2] += ts;

            #pragma unroll
            for (int t = 0; t < 4; ++t) {
                int lp = qcol + 16 * (2 * (t & 1) + (g >> 1));
                unsigned int w0, w1;
                asm("v_cvt_pk_bf16_f32 %0, %1, %2" : "=v"(w0) : "v"(p[t][0]), "v"(p[t][1]));
                asm("v_cvt_pk_bf16_f32 %0, %1, %2" : "=v"(w1) : "v"(p[t][2]), "v"(p[t][3]));
                unsigned int* dst = (unsigned int*)&pfrag[wid][qi2][t >> 1][lp][(g & 1) * 4];
                dst[0] = w0; dst[1] = w1;
            }
            bf16x8 pf0 = *(const bf16x8*)&pfrag[wid][qi2][0][lane][0];
            bf16x8 pf1 = *(const bf16x8*)&pfrag[wid][qi2][1][lane][0];

            acc[qi2][0] = __builtin_amdgcn_mfma_f32_16x16x32_bf16(v00, pf0, acc[qi2][0], 0, 0, 0);
            acc[qi2][0] = __builtin_amdgcn_mfma_f32_16x16x32_bf16(v10, pf1, acc[qi2][0], 0, 0, 0);
            acc[qi2][1] = __builtin_amdgcn_mfma_f32_16x16x32_bf16(v01, pf0, acc[qi2][1], 0, 0, 0);
            acc[qi2][1] = __builtin_amdgcn_mfma_f32_16x16x32_bf16(v11, pf1, acc[qi2][1], 0, 0, 0);
        }
    }

    // partial: [bh][qt][ks][qrow 16][32]: 0..29 acc(vd), 30 l
    #pragma unroll
    for (int qi2 = 0; qi2 < 2; ++qi2) {
        int qt = qtp * 2 + qi2;
        float* pp = part + ((size_t)((bh * 128 + qt) * NSPLIT + ks) * 16 + qcol) * 32;
        #pragma unroll
        for (int r = 0; r < 4; ++r) pp[g * 4 + r] = acc[qi2][0][r];
        if (g < 3) {
            #pragma unroll
            for (int r = 0; r < 4; ++r) pp[16 + g * 4 + r] = acc[qi2][1][r];
        } else {
            pp[28] = acc[qi2][1][0];
            pp[29] = acc[qi2][1][1];
            pp[30] = ll[qi2];
        }
    }
}

// ============================================================ combine + finalize
__global__ __launch_bounds__(128) void finalize_kernel(
    const float* __restrict__ part,
    const float* __restrict__ pos_CA, const float* __restrict__ pos_CB,
    const float* __restrict__ x,
    const float* __restrict__ Wo, const float* __restrict__ bo,
    const float* __restrict__ g1, const float* __restrict__ b1,
    const float* __restrict__ g2, const float* __restrict__ b2,
    float* __restrict__ out)
{
    int row0 = blockIdx.x * 2;
    int tid = threadIdx.x;
    __shared__ float fsL[2][FEAT];
    __shared__ float cawS[2][NHEADS][3];
    __shared__ float st[2][2][2];

    #pragma unroll
    for (int it = 0; it < 2; ++it) {
        int T = tid + it * 128;
        if (T < 240) {
            int r = T / 120, u = T % 120;
            int h = u / 30, vd = u % 30;
            int row = row0 + r;
            int b = row >> 11, n = row & (NB - 1);
            int bh = b * NHEADS + h;
            const float* pb = part + ((size_t)((bh * 128 + (n >> 4)) * NSPLIT) * 16 + (n & 15)) * 32;
            float A = 0.f, L = 0.f, A2 = 0.f;
            #pragma unroll 4
            for (int ks = 0; ks < NSPLIT; ++ks) {
                const float* pk = pb + ks * (16 * 32);
                A += pk[vd];
                L += pk[30];
                if (vd >= 24 && vd < 27) A2 += pk[vd + 3];
            }
            if (vd < 24) fsL[r][h * 24 + vd] = A / L;
            else if (vd < 27) cawS[r][h][vd - 24] = (A + A2) / L;
        }
    }
    __syncthreads();

    if (tid >= 96 && tid < 104) {
        int i2 = tid - 96;
        int r = i2 >> 2, h = i2 & 3;
        int row = row0 + r;
        int n = row & (NB - 1);
        float cax = pos_CA[(size_t)row * 3 + 0];
        float cay = pos_CA[(size_t)row * 3 + 1];
        float caz = pos_CA[(size_t)row * 3 + 2];
        float cbx = pos_CB[(size_t)row * 3 + 0];
        float cby = pos_CB[(size_t)row * 3 + 1];
        float cbz = pos_CB[(size_t)row * 3 + 2];
        float e1x = cbx - cax, e1y = cby - cay, e1z = cbz - caz;
        float n1 = sqrtf(e1x * e1x + e1y * e1y + e1z * e1z);
        bool valid1 = n1 > 1e-6f;
        float inv1 = 1.f / fmaxf(n1, 1e-12f);
        float ax = e1x * inv1, ay = e1y * inv1, az = e1z * inv1;
        float e2x = ay, e2y = -ax, e2z = 0.f;
        float n2a = sqrtf(e2x * e2x + e2y * e2y);
        if (n2a < 1e-6f) { e2x = -az; e2y = 0.f; e2z = ax; }
        float n2 = sqrtf(e2x * e2x + e2y * e2y + e2z * e2z);
        bool valid2 = n2 > 1e-6f;
        float inv2 = 1.f / fmaxf(n2, 1e-12f);
        float bx = e2x * inv2, by = e2y * inv2, bz = e2z * inv2;
        float cx = ay * bz - az * by;
        float cy = az * bx - ax * bz;
        float cz = ax * by - ay * bx;
        bool valid = valid1 && valid2 && (n < NB - 1);
        float F00, F01, F02, F10, F11, F12, F20, F21, F22;
        if (valid) { F00 = ax; F10 = ay; F20 = az;
                     F01 = bx; F11 = by; F21 = bz;
                     F02 = cx; F12 = cy; F22 = cz; }
        else { F00 = 1.f; F01 = 0.f; F02 = 0.f;
               F10 = 0.f; F11 = 1.f; F12 = 0.f;
               F20 = 0.f; F21 = 0.f; F22 = 1.f; }
        float b0 = cbx - cawS[r][h][0];
        float b1v = cby - cawS[r][h][1];
        float b2v = cbz - cawS[r][h][2];
        float dist = sqrtf(b0 * b0 + b1v * b1v + b2v * b2v);
        float p0 = F00 * b0 + F01 * b1v + F02 * b2v;
        float p1 = F10 * b0 + F11 * b1v + F12 * b2v;
        float p2 = F20 * b0 + F21 * b1v + F22 * b2v;
        float pn = sqrtf(p0 * p0 + p1 * p1 + p2 * p2);
        float invp = 1.f / (pn + 1e-10f);
        fsL[r][HID + h * 3 + 0] = p0;
        fsL[r][HID + h * 3 + 1] = p1;
        fsL[r][HID + h * 3 + 2] = p2;
        fsL[r][HID + 12 + h] = dist;
        fsL[r][HID + 16 + h * 3 + 0] = p0 * invp;
        fsL[r][HID + 16 + h * 3 + 1] = p1 * invp;
        fsL[r][HID + 16 + h * 3 + 2] = p2 * invp;
    }
    __syncthreads();

    float y0 = 0.f, y1 = 0.f;
    if (tid < HID) {
        float bj = bo[tid];
        y0 = bj; y1 = bj;
        #pragma unroll 4
        for (int i = 0; i < FEAT; ++i) {
            float w = Wo[i * HID + tid];
            y0 = fmaf(fsL[0][i], w, y0);
            y1 = fmaf(fsL[1][i], w, y1);
        }
    }

    {
        float s0 = y0, q0 = y0 * y0, s1 = y1, q1 = y1 * y1;
        #pragma unroll
        for (int d = 1; d < 64; d <<= 1) {
            s0 += __shfl_xor(s0, d, 64); q0 += __shfl_xor(q0, d, 64);
            s1 += __shfl_xor(s1, d, 64); q1 += __shfl_xor(q1, d, 64);
        }
        if ((tid & 63) == 0) {
            int w = tid >> 6;
            st[0][w][0] = s0; st[0][w][1] = q0;
            st[1][w][0] = s1; st[1][w][1] = q1;
        }
    }
    __syncthreads();
    float mean0 = (st[0][0][0] + st[0][1][0]) * (1.0f / HID);
    float var0  = (st[0][0][1] + st[0][1][1]) * (1.0f / HID) - mean0 * mean0;
    float mean1 = (st[1][0][0] + st[1][1][0]) * (1.0f / HID);
    float var1  = (st[1][0][1] + st[1][1][1]) * (1.0f / HID) - mean1 * mean1;
    __syncthreads();

    float r0 = 0.f, r1 = 0.f;
    if (tid < HID) {
        float gg = g1[tid], bb = b1[tid];
        float h0 = fmaxf((y0 - mean0) * rsqrtf(var0 + EPS_LN) * gg + bb, 0.f);
        float h1 = fmaxf((y1 - mean1) * rsqrtf(var1 + EPS_LN) * gg + bb, 0.f);
        r0 = x[(size_t)(row0 + 0) * HID + tid] + h0;
        r1 = x[(size_t)(row0 + 1) * HID + tid] + h1;
    }

    {
        float s0 = r0, q0 = r0 * r0, s1 = r1, q1 = r1 * r1;
        #pragma unroll
        for (int d = 1; d < 64; d <<= 1) {
            s0 += __shfl_xor(s0, d, 64); q0 += __shfl_xor(q0, d, 64);
            s1 += __shfl_xor(s1, d, 64); q1 += __shfl_xor(q1, d, 64);
        }
        if ((tid & 63) == 0) {
            int w = tid >> 6;
            st[0][w][0] = s0; st[0][w][1] = q0;
            st[1][w][0] = s1; st[1][w][1] = q1;
        }
    }
    __syncthreads();
    mean0 = (st[0][0][0] + st[0][1][0]) * (1.0f / HID);
    var0  = (st[0][0][1] + st[0][1][1]) * (1.0f / HID) - mean0 * mean0;
    mean1 = (st[1][0][0] + st[1][1][0]) * (1.0f / HID);
    var1  = (st[1][0][1] + st[1][1][1]) * (1.0f / HID) - mean1 * mean1;

    if (tid < HID) {
        out[(size_t)(row0 + 0) * HID + tid] =
            (r0 - mean0) * rsqrtf(var0 + EPS_LN) * g2[tid] + b2[tid];
        out[(size_t)(row0 + 1) * HID + tid] =
            (r1 - mean1) * rsqrtf(var1 + EPS_LN) * g2[tid] + b2[tid];
    }
}

// ============================================================ launch
extern "C" void kernel_launch(void* const* d_in, const int* in_sizes, int n_in,
                              void* d_out, int out_size, void* d_ws, size_t ws_size,
                              hipStream_t stream)
{
    const float* x      = (const float*)d_in[0];
    const float* pos_CA = (const float*)d_in[1];
    const float* pos_CB = (const float*)d_in[2];
    const float* Wq = (const float*)d_in[4],  *bq = (const float*)d_in[5];
    const float* Wk = (const float*)d_in[6],  *bk = (const float*)d_in[7];
    const float* Wv = (const float*)d_in[8],  *bv = (const float*)d_in[9];
    const float* Wo = (const float*)d_in[10], *bo = (const float*)d_in[11];
    const float* g1 = (const float*)d_in[12], *b1 = (const float*)d_in[13];
    const float* g2 = (const float*)d_in[14], *b2 = (const float*)d_in[15];
    float* out = (float*)d_out;

    const size_t FR = 524288;                 // ushorts per frag array (1 MB)
    unsigned short* khi = (unsigned short*)d_ws;
    unsigned short* qhi = khi + FR;
    unsigned short* qlo = khi + 2 * FR;
    unsigned short* vfr = khi + 3 * FR;
    const size_t FRAG_BYTES = 4 * FR * 2;     // 4 MB
    float* part = (float*)((char*)d_ws + FRAG_BYTES);   // 33.6 MB

    hipLaunchKernelGGL(qkvfrag_kernel, dim3(256 * 3), dim3(64), 0, stream,
                       x, pos_CA, Wq, bq, Wk, bk, Wv, bv, khi, qhi, qlo, vfr);
    int nblocks = (8 * 64 * NSPLIT) / 4;      // 8192 wave-tasks, 4 waves/block
    hipLaunchKernelGGL(attn_mfma_kernel, dim3(nblocks), dim3(256), 0, stream,
                       khi, qhi, qlo, vfr, part);
    hipLaunchKernelGGL(finalize_kernel, dim3(NROWS / 2), dim3(128), 0, stream,
                       part, pos_CA, pos_CB, x, Wo, bo, g1, b1, g2, b2, out);
}